// Round 1
// baseline (115.427 us; speedup 1.0000x reference)
//
#include <hip/hip_runtime.h>
#include <hip/hip_bf16.h>

typedef short bf16x8 __attribute__((ext_vector_type(8)));
typedef short bf16x4 __attribute__((ext_vector_type(4)));
typedef float f32x4  __attribute__((ext_vector_type(4)));

__device__ __forceinline__ unsigned short f2bf(float f) {
    union { float fv; unsigned int u; } v; v.fv = f;
    unsigned int r = v.u + 0x7FFFu + ((v.u >> 16) & 1u);
    return (unsigned short)(r >> 16);
}

// ---- prep: transpose + convert weights to bf16 [N][K] ----
__global__ __launch_bounds__(256) void prep_w(
    const float* __restrict__ Wqkv, const float* __restrict__ Wout,
    short* __restrict__ Wqkvt, short* __restrict__ Woutt)
{
    int idx = blockIdx.x * 256 + threadIdx.x;   // 0 .. 786431
    int n = idx >> 9, k = idx & 511;
    Wqkvt[idx] = (short)f2bf(Wqkv[(size_t)k * 1536 + n]);
    if (idx < 512 * 512) {
        Woutt[idx] = (short)f2bf(Wout[(size_t)k * 512 + n]);
    }
}

// ---- GEMM: C[M,N] = A[M,K] * Bt[N,K]^T ----
// A_F32: A is f32 (converted to bf16 during staging), else bf16.
// F32OUT: write f32 + bias, else bf16.
template<int A_F32, int F32OUT>
__global__ __launch_bounds__(256) void gemm_bt(
    const void* __restrict__ Ain, const short* __restrict__ Bt,
    short* __restrict__ Cb, float* __restrict__ Cf, const float* __restrict__ bias,
    int M, int N, int K)
{
    __shared__ short As[128][72];   // pad: row stride 144B (16B-aligned, 2-way max)
    __shared__ short Bs[128][72];
    const int t    = threadIdx.x;
    const int lane = t & 63;
    const int wid  = t >> 6;
    const int l15  = lane & 15;
    const int lg   = lane >> 4;
    const int m0 = blockIdx.x * 128;
    const int n0 = blockIdx.y * 128;
    const int wm = (wid >> 1) * 64;
    const int wn = (wid & 1) * 64;
    const int srow = t >> 3;   // 0..31
    const int sseg = t & 7;    // 0..7

    f32x4 acc[4][4];
    #pragma unroll
    for (int i = 0; i < 4; ++i)
        #pragma unroll
        for (int j = 0; j < 4; ++j)
            acc[i][j] = f32x4{0.f, 0.f, 0.f, 0.f};

    for (int k0 = 0; k0 < K; k0 += 64) {
        #pragma unroll
        for (int it = 0; it < 4; ++it) {
            const int row = srow + it * 32;
            if constexpr (A_F32) {
                const float* Af = (const float*)Ain;
                const float* src = Af + (size_t)(m0 + row) * K + k0 + sseg * 8;
                f32x4 v0 = *(const f32x4*)(src);
                f32x4 v1 = *(const f32x4*)(src + 4);
                bf16x8 s;
                #pragma unroll
                for (int e = 0; e < 4; ++e) s[e] = (short)f2bf(v0[e]);
                #pragma unroll
                for (int e = 0; e < 4; ++e) s[4 + e] = (short)f2bf(v1[e]);
                *(bf16x8*)&As[row][sseg * 8] = s;
            } else {
                const short* Ab = (const short*)Ain;
                *(bf16x8*)&As[row][sseg * 8] =
                    *(const bf16x8*)(Ab + (size_t)(m0 + row) * K + k0 + sseg * 8);
            }
            *(bf16x8*)&Bs[row][sseg * 8] =
                *(const bf16x8*)(Bt + (size_t)(n0 + row) * K + k0 + sseg * 8);
        }
        __syncthreads();

        bf16x8 af[4][2], bg[4][2];
        #pragma unroll
        for (int mi = 0; mi < 4; ++mi)
            #pragma unroll
            for (int kf = 0; kf < 2; ++kf)
                af[mi][kf] = *(const bf16x8*)&As[wm + mi * 16 + l15][kf * 32 + 8 * lg];
        #pragma unroll
        for (int ni = 0; ni < 4; ++ni)
            #pragma unroll
            for (int kf = 0; kf < 2; ++kf)
                bg[ni][kf] = *(const bf16x8*)&Bs[wn + ni * 16 + l15][kf * 32 + 8 * lg];

        #pragma unroll
        for (int kf = 0; kf < 2; ++kf)
            #pragma unroll
            for (int mi = 0; mi < 4; ++mi)
                #pragma unroll
                for (int ni = 0; ni < 4; ++ni)
                    acc[mi][ni] = __builtin_amdgcn_mfma_f32_16x16x32_bf16(
                        af[mi][kf], bg[ni][kf], acc[mi][ni], 0, 0, 0);
        __syncthreads();
    }

    #pragma unroll
    for (int mi = 0; mi < 4; ++mi) {
        #pragma unroll
        for (int ni = 0; ni < 4; ++ni) {
            const int col = n0 + wn + ni * 16 + l15;
            #pragma unroll
            for (int r = 0; r < 4; ++r) {
                const int rowi = m0 + wm + mi * 16 + 4 * lg + r;
                if constexpr (F32OUT) {
                    Cf[(size_t)rowi * N + col] = acc[mi][ni][r] + bias[col];
                } else {
                    Cb[(size_t)rowi * N + col] = (short)f2bf(acc[mi][ni][r]);
                }
            }
        }
    }
}

// ---- fused attention: one block per (b*p, head); 8 waves x 64 q-rows ----
// qkv: [16384][1536] bf16 (q|k|v each 512 cols, head h at h*64).
// attn_out: [16384][512] bf16, col = h*64 + d.
__global__ __launch_bounds__(512) void attn_kernel(
    const short* __restrict__ qkv, short* __restrict__ attn_out)
{
    __shared__ short Kl[64][72];   // K tile  [kv][d], stride 144B
    __shared__ short Vt[64][76];   // V^T tile [d][kv], stride 152B (conflict fix)
    const int t    = threadIdx.x;
    const int lane = t & 63;
    const int wid  = t >> 6;
    const int l15  = lane & 15;
    const int lg   = lane >> 4;
    const int bph = blockIdx.x;
    const int bp = bph >> 3, h = bph & 7;
    const size_t tok0 = (size_t)bp * 512;
    const int q0   = wid * 64;
    const int qcol = h * 64;

    // Q fragments in registers: B-operand layout (col m = l15, k(d) = 8*lg+e)
    bf16x8 qf[4][2];
    #pragma unroll
    for (int mj = 0; mj < 4; ++mj)
        #pragma unroll
        for (int kf = 0; kf < 2; ++kf)
            qf[mj][kf] = *(const bf16x8*)(qkv + (tok0 + q0 + mj * 16 + l15) * 1536
                                          + qcol + kf * 32 + 8 * lg);

    f32x4 ot[4][4];   // O^T accum [di][mj]
    #pragma unroll
    for (int i = 0; i < 4; ++i)
        #pragma unroll
        for (int j = 0; j < 4; ++j)
            ot[i][j] = f32x4{0.f, 0.f, 0.f, 0.f};
    float mrun[4], lrun[4];
    #pragma unroll
    for (int mj = 0; mj < 4; ++mj) { mrun[mj] = -1e30f; lrun[mj] = 0.f; }

    const int sn = t >> 3;         // 0..63  (kv row)
    const int sd = (t & 7) * 8;    // 0..56  (d octet)

    for (int kv0 = 0; kv0 < 512; kv0 += 64) {
        // stage K and V^T
        const short* kvrow = qkv + (tok0 + kv0 + sn) * 1536;
        *(bf16x8*)&Kl[sn][sd] = *(const bf16x8*)(kvrow + 512 + qcol + sd);
        bf16x8 vv = *(const bf16x8*)(kvrow + 1024 + qcol + sd);
        #pragma unroll
        for (int i = 0; i < 8; ++i) Vt[sd + i][sn] = vv[i];
        __syncthreads();

        // S^T[n][m] = sum_d K[n][d] Q[m][d]   (A = K, B = Q)
        f32x4 st[4][4];   // [ni][mj]
        #pragma unroll
        for (int i = 0; i < 4; ++i)
            #pragma unroll
            for (int j = 0; j < 4; ++j)
                st[i][j] = f32x4{0.f, 0.f, 0.f, 0.f};
        #pragma unroll
        for (int kf = 0; kf < 2; ++kf) {
            #pragma unroll
            for (int ni = 0; ni < 4; ++ni) {
                bf16x8 kfr = *(const bf16x8*)&Kl[ni * 16 + l15][kf * 32 + 8 * lg];
                #pragma unroll
                for (int mj = 0; mj < 4; ++mj)
                    st[ni][mj] = __builtin_amdgcn_mfma_f32_16x16x32_bf16(
                        kfr, qf[mj][kf], st[ni][mj], 0, 0, 0);
            }
        }

        // online softmax per q-row (col m = l15, all reduces in 16-lane xor groups)
        #pragma unroll
        for (int mj = 0; mj < 4; ++mj) {
            float pm = -1e30f;
            #pragma unroll
            for (int ni = 0; ni < 4; ++ni)
                #pragma unroll
                for (int r = 0; r < 4; ++r) {
                    st[ni][mj][r] *= 0.125f;   // SCALE = dim_head^-0.5
                    pm = fmaxf(pm, st[ni][mj][r]);
                }
            pm = fmaxf(pm, __shfl_xor(pm, 16));
            pm = fmaxf(pm, __shfl_xor(pm, 32));
            const float mnew = fmaxf(mrun[mj], pm);
            const float fsc  = __expf(mrun[mj] - mnew);
            float ps = 0.f;
            #pragma unroll
            for (int ni = 0; ni < 4; ++ni)
                #pragma unroll
                for (int r = 0; r < 4; ++r) {
                    float e = __expf(st[ni][mj][r] - mnew);
                    st[ni][mj][r] = e;
                    ps += e;
                }
            ps += __shfl_xor(ps, 16);
            ps += __shfl_xor(ps, 32);
            lrun[mj] = lrun[mj] * fsc + ps;
            mrun[mj] = mnew;
            #pragma unroll
            for (int di = 0; di < 4; ++di)
                ot[di][mj] *= fsc;
        }

        // O^T[d][m] += sum_n V^T[d][n] P^T[n][m]
        // P^T D-frag (row n = 4*lg+reg) IS the 16x16x16 B-operand layout.
        #pragma unroll
        for (int ni = 0; ni < 4; ++ni) {
            bf16x4 pb[4];
            #pragma unroll
            for (int mj = 0; mj < 4; ++mj)
                #pragma unroll
                for (int r = 0; r < 4; ++r)
                    pb[mj][r] = (short)f2bf(st[ni][mj][r]);
            #pragma unroll
            for (int di = 0; di < 4; ++di) {
                bf16x4 av = *(const bf16x4*)&Vt[di * 16 + l15][ni * 16 + 4 * lg];
                #pragma unroll
                for (int mj = 0; mj < 4; ++mj)
                    ot[di][mj] = __builtin_amdgcn_mfma_f32_16x16x16bf16_1k(
                        av, pb[mj], ot[di][mj], 0, 0, 0);
            }
        }
        __syncthreads();
    }

    float inv[4];
    #pragma unroll
    for (int mj = 0; mj < 4; ++mj) inv[mj] = 1.f / lrun[mj];
    #pragma unroll
    for (int di = 0; di < 4; ++di)
        #pragma unroll
        for (int mj = 0; mj < 4; ++mj) {
            const size_t tok = tok0 + q0 + mj * 16 + l15;
            const int col = qcol + di * 16 + 4 * lg;
            bf16x4 o4;
            #pragma unroll
            for (int r = 0; r < 4; ++r)
                o4[r] = (short)f2bf(ot[di][mj][r] * inv[mj]);
            *(bf16x4*)(attn_out + tok * 512 + col) = o4;
        }
}

extern "C" void kernel_launch(void* const* d_in, const int* in_sizes, int n_in,
                              void* d_out, int out_size, void* d_ws, size_t ws_size,
                              hipStream_t stream) {
    const float* x    = (const float*)d_in[0];   // [16384][512]
    const float* Wqkv = (const float*)d_in[1];   // [512][1536]
    const float* Wout = (const float*)d_in[2];   // [512][512]
    const float* bout = (const float*)d_in[3];   // [512]
    float* out = (float*)d_out;                  // [16384][512] f32

    char* ws = (char*)d_ws;
    short* qkvb  = (short*)(ws);                          // 48 MB  [16384][1536] bf16
    short* attnb = (short*)(ws + 50331648ull);            // 16 MB  [16384][512]  bf16
    short* Wqkvt = (short*)(ws + 67108864ull);            // 1.5 MB [1536][512]   bf16
    short* Woutt = (short*)(ws + 68681728ull);            // 0.5 MB [512][512]    bf16

    prep_w<<<3072, 256, 0, stream>>>(Wqkv, Wout, Wqkvt, Woutt);

    dim3 g1(128, 12);   // M=16384, N=1536
    gemm_bt<1, 0><<<g1, 256, 0, stream>>>((const void*)x, Wqkvt, qkvb, nullptr, nullptr,
                                          16384, 1536, 512);

    attn_kernel<<<256, 512, 0, stream>>>(qkvb, attnb);

    dim3 g2(128, 4);    // M=16384, N=512
    gemm_bt<0, 1><<<g2, 256, 0, stream>>>((const void*)attnb, Woutt, nullptr, out, bout,
                                          16384, 512, 512);
}